// Round 1
// baseline (892.303 us; speedup 1.0000x reference)
//
#include <hip/hip_runtime.h>
#include <cstdint>

// ---------------------------------------------------------------------------
// GATv2 x2 (PyG semantics) for MI355X.
// Pipeline:
//   1. CSR-by-dst build: histogram -> scan -> scatter  (edge ids kept)
//   2. dual GEMM: xlr[N][256] = X @ [W_l | W_r]  (fp32, 64x64 tile, 4x4 micro)
//   3. edge kernel: one wave per dst node, online softmax, writes node feats,
//      stores logits e per edge (layer 1 only) for alpha export
//   4. alpha kernel: alpha[i] = exp(e_i - m[dst]) / den[dst], original order
//   5. repeat GEMM+edge for layer 2 (adds bias2 + mmse embedding)
// ---------------------------------------------------------------------------

__global__ void hist_kernel(const int* __restrict__ ei, int E, int N,
                            int* __restrict__ counts) {
  const int total = E + N;
  for (int i = blockIdx.x * blockDim.x + threadIdx.x; i < total;
       i += gridDim.x * blockDim.x) {
    const int d = (i < E) ? ei[E + i] : (i - E);
    atomicAdd(&counts[d], 1);
  }
}

__global__ void scan_kernel(const int* __restrict__ counts,
                            int* __restrict__ row_ptr,
                            int* __restrict__ cursor, int N) {
  __shared__ int sums[257];
  const int tid = threadIdx.x;  // 256 threads
  const int chunk = (N + 255) / 256;
  const int lo = tid * chunk;
  const int hi = min(lo + chunk, N);
  int s = 0;
  for (int i = lo; i < hi; ++i) s += counts[i];
  sums[tid + 1] = s;
  if (tid == 0) sums[0] = 0;
  __syncthreads();
  if (tid == 0) {
    for (int i = 1; i <= 256; ++i) sums[i] += sums[i - 1];
  }
  __syncthreads();
  int run = sums[tid];
  for (int i = lo; i < hi; ++i) {
    row_ptr[i] = run;
    cursor[i] = run;
    run += counts[i];
  }
  if (tid == 255) row_ptr[N] = sums[256];
}

__global__ void scatter_kernel(const int* __restrict__ ei, int E, int N,
                               int* __restrict__ cursor,
                               int* __restrict__ csr_src,
                               int* __restrict__ csr_eid) {
  const int total = E + N;
  for (int i = blockIdx.x * blockDim.x + threadIdx.x; i < total;
       i += gridDim.x * blockDim.x) {
    int s, d;
    if (i < E) { s = ei[i]; d = ei[E + i]; } else { s = d = i - E; }
    const int pos = atomicAdd(&cursor[d], 1);
    csr_src[pos] = s;
    csr_eid[pos] = i;
  }
}

__global__ void mmse_kernel(const float* __restrict__ score,
                            const float* __restrict__ W,
                            const float* __restrict__ b,
                            float* __restrict__ out, int D) {
  const int i = threadIdx.x;
  if (i < D) out[i] = score[0] * W[i] + b[i];
}

// out[M][256] = X[M][K] @ [Wl | Wr]   (each [K][128] row-major)
__global__ __launch_bounds__(256) void gemm_dual(
    const float* __restrict__ X, const float* __restrict__ Wl,
    const float* __restrict__ Wr, float* __restrict__ out, int M, int K) {
  constexpr int BM = 64, BN = 64, BK = 16;
  __shared__ float a_lds[BK][BM];
  __shared__ float b_lds[BK][BN];

  const int mblk = blockIdx.x;
  const int nblk = blockIdx.y;  // 0..3 : {Wl lo, Wl hi, Wr lo, Wr hi}
  const float* __restrict__ W = (nblk < 2) ? Wl : Wr;
  const int wcol0 = (nblk & 1) * 64;  // within W (ld = 128)
  const int row0 = mblk * BM;

  const int tid = threadIdx.x;
  const int ty = tid >> 4;   // 0..15
  const int tx = tid & 15;   // 0..15

  const int ar = tid >> 2;         // 0..63 rows of A tile
  const int ak = (tid & 3) * 4;    // k offset of A tile
  const int bk = tid >> 4;         // 0..15 k rows of B tile
  const int bc = (tid & 15) * 4;   // col offset of B tile

  const int arow = min(row0 + ar, M - 1);

  float acc[4][4] = {};

  for (int k0 = 0; k0 < K; k0 += BK) {
    const float4 av = *(const float4*)&X[(size_t)arow * K + k0 + ak];
    const float4 bv = *(const float4*)&W[(size_t)(k0 + bk) * 128 + wcol0 + bc];
    __syncthreads();
    a_lds[ak + 0][ar] = av.x;
    a_lds[ak + 1][ar] = av.y;
    a_lds[ak + 2][ar] = av.z;
    a_lds[ak + 3][ar] = av.w;
    *(float4*)&b_lds[bk][bc] = bv;
    __syncthreads();
#pragma unroll
    for (int k = 0; k < BK; ++k) {
      const float4 a = *(const float4*)&a_lds[k][ty * 4];
      const float4 b = *(const float4*)&b_lds[k][tx * 4];
      acc[0][0] += a.x * b.x; acc[0][1] += a.x * b.y;
      acc[0][2] += a.x * b.z; acc[0][3] += a.x * b.w;
      acc[1][0] += a.y * b.x; acc[1][1] += a.y * b.y;
      acc[1][2] += a.y * b.z; acc[1][3] += a.y * b.w;
      acc[2][0] += a.z * b.x; acc[2][1] += a.z * b.y;
      acc[2][2] += a.z * b.z; acc[2][3] += a.z * b.w;
      acc[3][0] += a.w * b.x; acc[3][1] += a.w * b.y;
      acc[3][2] += a.w * b.z; acc[3][3] += a.w * b.w;
    }
  }

#pragma unroll
  for (int i = 0; i < 4; ++i) {
    const int r = row0 + ty * 4 + i;
    if (r < M) {
      float4 v;
      v.x = acc[i][0]; v.y = acc[i][1]; v.z = acc[i][2]; v.w = acc[i][3];
      *(float4*)&out[(size_t)r * 256 + nblk * 64 + tx * 4] = v;
    }
  }
}

// One wave per dst node; lane owns dims {2*lane, 2*lane+1}. Online softmax.
__global__ __launch_bounds__(256) void gat_edge(
    const float* __restrict__ xlr,      // [N][256]: cols 0..127 = x_l, 128..255 = x_r
    const int* __restrict__ row_ptr, const int* __restrict__ csr_src,
    const int* __restrict__ csr_eid, const float* __restrict__ att,
    const float* __restrict__ bias, const float* __restrict__ extra,
    float* __restrict__ node_out,       // [N][128]
    float* __restrict__ e_ws, float* __restrict__ m_ws,
    float* __restrict__ den_ws, int N) {
  const int wave = threadIdx.x >> 6;
  const int lane = threadIdx.x & 63;
  const int node = blockIdx.x * 4 + wave;
  if (node >= N) return;

  const int d0 = lane * 2;
  const float2 attv = *(const float2*)&att[d0];
  const float2 xrv = *(const float2*)&xlr[(size_t)node * 256 + 128 + d0];

  float m = -1e30f, den = 0.f;
  float2 acc = make_float2(0.f, 0.f);

  const int beg = row_ptr[node];
  const int end = row_ptr[node + 1];
  for (int idx = beg; idx < end; ++idx) {
    const int s = csr_src[idx];
    const float2 xl = *(const float2*)&xlr[(size_t)s * 256 + d0];
    float hx = xl.x + xrv.x;
    float hy = xl.y + xrv.y;
    hx = hx > 0.f ? hx : 0.2f * hx;
    hy = hy > 0.f ? hy : 0.2f * hy;
    float p = hx * attv.x + hy * attv.y;
#pragma unroll
    for (int off = 32; off; off >>= 1) p += __shfl_xor(p, off);
    if (e_ws != nullptr && lane == 0) e_ws[csr_eid[idx]] = p;
    if (p > m) {
      const float f = __expf(m - p);  // 0 on first edge (m = -1e30)
      den = den * f + 1.f;
      acc.x = acc.x * f + xl.x;
      acc.y = acc.y * f + xl.y;
      m = p;
    } else {
      const float w = __expf(p - m);
      den += w;
      acc.x += w * xl.x;
      acc.y += w * xl.y;
    }
  }

  const float inv = 1.f / den;
  float ox = acc.x * inv + bias[d0];
  float oy = acc.y * inv + bias[d0 + 1];
  if (extra != nullptr) { ox += extra[d0]; oy += extra[d0 + 1]; }
  *(float2*)&node_out[(size_t)node * 128 + d0] = make_float2(ox, oy);
  if (m_ws != nullptr && lane == 0) {
    m_ws[node] = m;
    den_ws[node] = den;
  }
}

__global__ void alpha_kernel(const float* __restrict__ e_ws,
                             const float* __restrict__ m_ws,
                             const float* __restrict__ den_ws,
                             const int* __restrict__ ei, int E, int N,
                             float* __restrict__ out_alpha) {
  const int i = blockIdx.x * blockDim.x + threadIdx.x;
  if (i >= E + N) return;
  const int d = (i < E) ? ei[E + i] : (i - E);
  out_alpha[i] = __expf(e_ws[i] - m_ws[d]) / den_ws[d];
}

extern "C" void kernel_launch(void* const* d_in, const int* in_sizes, int n_in,
                              void* d_out, int out_size, void* d_ws,
                              size_t ws_size, hipStream_t stream) {
  const float* x          = (const float*)d_in[0];
  const int*   ei         = (const int*)d_in[1];
  const float* mmse_score = (const float*)d_in[2];
  const float* W_l1       = (const float*)d_in[3];
  const float* W_r1       = (const float*)d_in[4];
  const float* att1       = (const float*)d_in[5];
  const float* bias1      = (const float*)d_in[6];
  const float* W_l2       = (const float*)d_in[7];
  const float* W_r2       = (const float*)d_in[8];
  const float* att2       = (const float*)d_in[9];
  const float* bias2      = (const float*)d_in[10];
  const float* mmse_W     = (const float*)d_in[11];
  const float* mmse_b     = (const float*)d_in[12];

  const int D  = in_sizes[5];        // 128
  const int T  = in_sizes[3] / D;    // 512
  const int N  = in_sizes[0] / T;    // 50000
  const int E  = in_sizes[1] / 2;    // 800000
  const int ET = E + N;              // 850000 (with self-loops)

  // workspace carve-out (~88 MB)
  char* w = (char*)d_ws;
  auto alloc = [&](size_t bytes) {
    char* p = w;
    w += (bytes + 255) & ~(size_t)255;
    return p;
  };
  float* xlr      = (float*)alloc((size_t)N * 256 * 4);  // [N][256] l|r
  float* attn1    = (float*)alloc((size_t)N * 128 * 4);
  float* e_ws     = (float*)alloc((size_t)ET * 4);
  float* m_ws     = (float*)alloc((size_t)N * 4);
  float* den_ws   = (float*)alloc((size_t)N * 4);
  float* mmse_vec = (float*)alloc(512);
  int* counts  = (int*)alloc((size_t)N * 4);
  int* row_ptr = (int*)alloc((size_t)(N + 1) * 4);
  int* cursor  = (int*)alloc((size_t)N * 4);
  int* csr_src = (int*)alloc((size_t)ET * 4);
  int* csr_eid = (int*)alloc((size_t)ET * 4);

  float* out_feat  = (float*)d_out;             // N*128
  float* out_alpha = out_feat + (size_t)N * D;  // ET

  // 1. CSR by dst
  hipMemsetAsync(counts, 0, (size_t)N * 4, stream);
  hist_kernel<<<2048, 256, 0, stream>>>(ei, E, N, counts);
  scan_kernel<<<1, 256, 0, stream>>>(counts, row_ptr, cursor, N);
  scatter_kernel<<<2048, 256, 0, stream>>>(ei, E, N, cursor, csr_src, csr_eid);

  // 2. layer-1 GEMMs + mmse embedding
  dim3 g1((N + 63) / 64, 4);
  gemm_dual<<<g1, 256, 0, stream>>>(x, W_l1, W_r1, xlr, N, T);
  mmse_kernel<<<1, 128, 0, stream>>>(mmse_score, mmse_W, mmse_b, mmse_vec, D);

  // 3. layer-1 edge phase (stores logits + softmax stats for alpha export)
  gat_edge<<<(N + 3) / 4, 256, 0, stream>>>(xlr, row_ptr, csr_src, csr_eid,
                                            att1, bias1, nullptr, attn1, e_ws,
                                            m_ws, den_ws, N);

  // 4. alpha in original edge order
  alpha_kernel<<<(ET + 255) / 256, 256, 0, stream>>>(e_ws, m_ws, den_ws, ei, E,
                                                     N, out_alpha);

  // 5. layer 2 (xlr buffer reused)
  gemm_dual<<<g1, 256, 0, stream>>>(attn1, W_l2, W_r2, xlr, N, D);
  gat_edge<<<(N + 3) / 4, 256, 0, stream>>>(xlr, row_ptr, csr_src, csr_eid,
                                            att2, bias2, mmse_vec, out_feat,
                                            nullptr, nullptr, nullptr, N);
}

// Round 3
// 683.217 us; speedup vs baseline: 1.3060x; 1.3060x over previous
//
#include <hip/hip_runtime.h>
#include <cstdint>

typedef __bf16 bf16;
typedef __bf16 bf16x8 __attribute__((ext_vector_type(8)));
typedef float f32x4 __attribute__((ext_vector_type(4)));

__device__ __forceinline__ void load_lds16(const void* g, void* l) {
  __builtin_amdgcn_global_load_lds(
      (const __attribute__((address_space(1))) void*)g,
      (__attribute__((address_space(3))) void*)l, 16, 0, 0);
}

__device__ __forceinline__ unsigned short bf16_bits(float f) {
  return __builtin_bit_cast(unsigned short, (bf16)f);
}

// ---------------------------------------------------------------------------
// CSR-by-dst build
// ---------------------------------------------------------------------------
__global__ void hist_kernel(const int* __restrict__ ei, int E, int N,
                            int* __restrict__ counts) {
  const int total = E + N;
  for (int i = blockIdx.x * blockDim.x + threadIdx.x; i < total;
       i += gridDim.x * blockDim.x) {
    const int d = (i < E) ? ei[E + i] : (i - E);
    atomicAdd(&counts[d], 1);
  }
}

__global__ void scan_kernel(const int* __restrict__ counts,
                            int* __restrict__ row_ptr,
                            int* __restrict__ cursor, int N) {
  __shared__ int sums[257];
  const int tid = threadIdx.x;  // 256 threads
  const int chunk = (N + 255) / 256;
  const int lo = tid * chunk;
  const int hi = min(lo + chunk, N);
  int s = 0;
  for (int i = lo; i < hi; ++i) s += counts[i];
  sums[tid + 1] = s;
  if (tid == 0) sums[0] = 0;
  __syncthreads();
  if (tid == 0) {
    for (int i = 1; i <= 256; ++i) sums[i] += sums[i - 1];
  }
  __syncthreads();
  int run = sums[tid];
  for (int i = lo; i < hi; ++i) {
    row_ptr[i] = run;
    cursor[i] = run;
    run += counts[i];
  }
  if (tid == 255) row_ptr[N] = sums[256];
}

__global__ void scatter_kernel(const int* __restrict__ ei, int E, int N,
                               int* __restrict__ cursor,
                               int* __restrict__ csr_src,
                               int* __restrict__ csr_eid) {
  const int total = E + N;
  for (int i = blockIdx.x * blockDim.x + threadIdx.x; i < total;
       i += gridDim.x * blockDim.x) {
    int s, d;
    if (i < E) { s = ei[i]; d = ei[E + i]; } else { s = d = i - E; }
    const int pos = atomicAdd(&cursor[d], 1);
    csr_src[pos] = s;
    csr_eid[pos] = i;
  }
}

// ---------------------------------------------------------------------------
// small helpers
// ---------------------------------------------------------------------------
__global__ void mmse_kernel(const float* __restrict__ score,
                            const float* __restrict__ W,
                            const float* __restrict__ b,
                            float* __restrict__ out, int D) {
  const int i = threadIdx.x;
  if (i < D) out[i] = score[0] * W[i] + b[i];
}

// Wt[col][k] (col-major weights, bf16), col in [0,256): 0..127 = W_l, 128..255 = W_r
__global__ void wt_kernel(const float* __restrict__ Wl,
                          const float* __restrict__ Wr,
                          bf16* __restrict__ Wt, int K) {
  const int idx = blockIdx.x * blockDim.x + threadIdx.x;
  if (idx >= 256 * K) return;
  const int col = idx & 255;
  const int k = idx >> 8;
  const float v = (col < 128) ? Wl[k * 128 + col] : Wr[k * 128 + (col - 128)];
  Wt[(size_t)col * K + k] = (bf16)v;
}

// ---------------------------------------------------------------------------
// MFMA GEMM: [xl | xr] = A[M][K] @ Wt^T   (Wt is [256][K] bf16, col-major W)
// BM=128, BN=256, BK=32; 512 threads = 8 waves (2x4), 64x64 per wave.
// A is reg-staged (with fp32->bf16 convert when AF32); B via global_load_lds.
// ---------------------------------------------------------------------------
template <bool AF32>
__global__ __launch_bounds__(512) void gemm_mfma(
    const void* __restrict__ Ap, const bf16* __restrict__ Wt,
    bf16* __restrict__ xl, bf16* __restrict__ xr, int M, int K) {
  __shared__ __align__(16) bf16 Alds[128 * 32];
  __shared__ __align__(16) bf16 Blds[256 * 32];

  const int tid = threadIdx.x;
  const int w = tid >> 6, lane = tid & 63;
  const int wr = w >> 2, wc = w & 3;  // 2 x 4 waves
  const int row0 = blockIdx.x * 128;

  // A staging: thread t -> row t/4, k-offset (t&3)*8 (elements). LDS linear.
  const int s_row = tid >> 2;
  const int s_k = (tid & 3) * 8;
  const int a_row = min(row0 + s_row, M - 1);
  bf16* a_dst = Alds + tid * 8;

  // B staging: wave w covers cols [w*32, w*32+32) in two 1 KiB chunks.
  const int b_col0 = w * 32 + (lane >> 2);
  const bf16* b_src0 = Wt + (size_t)b_col0 * K + (lane & 3) * 8;
  const bf16* b_src1 = Wt + (size_t)(b_col0 + 16) * K + (lane & 3) * 8;
  bf16* b_dst0 = Blds + w * 1024 + lane * 8;
  bf16* b_dst1 = b_dst0 + 512;

  // fragment read offsets (elements)
  const int a_f0 = (wr * 64 + (lane & 15)) * 32 + (lane >> 4) * 8;
  const int b_f0 = (wc * 64 + (lane & 15)) * 32 + (lane >> 4) * 8;

  f32x4 acc[4][4] = {};

  for (int k0 = 0; k0 < K; k0 += 32) {
    bf16x8 av;
    if (AF32) {
      const float* A = (const float*)Ap;
      const float4 f0 = *(const float4*)&A[(size_t)a_row * K + k0 + s_k];
      const float4 f1 = *(const float4*)&A[(size_t)a_row * K + k0 + s_k + 4];
      av[0] = (bf16)f0.x; av[1] = (bf16)f0.y; av[2] = (bf16)f0.z; av[3] = (bf16)f0.w;
      av[4] = (bf16)f1.x; av[5] = (bf16)f1.y; av[6] = (bf16)f1.z; av[7] = (bf16)f1.w;
    } else {
      av = *(const bf16x8*)((const bf16*)Ap + (size_t)a_row * K + k0 + s_k);
    }
    __syncthreads();  // previous iteration's readers done
    *(bf16x8*)a_dst = av;
    load_lds16(b_src0 + k0, b_dst0);
    load_lds16(b_src1 + k0, b_dst1);
    __syncthreads();  // tile ready (drains vmcnt + lgkmcnt)

    bf16x8 af[4], bfr[4];
#pragma unroll
    for (int m = 0; m < 4; ++m) af[m] = *(const bf16x8*)(Alds + a_f0 + m * 512);
#pragma unroll
    for (int n = 0; n < 4; ++n) bfr[n] = *(const bf16x8*)(Blds + b_f0 + n * 512);
#pragma unroll
    for (int m = 0; m < 4; ++m)
#pragma unroll
      for (int n = 0; n < 4; ++n)
        acc[m][n] = __builtin_amdgcn_mfma_f32_16x16x32_bf16(af[m], bfr[n],
                                                            acc[m][n], 0, 0, 0);
  }

  // epilogue: C[row, col] -> xl (col<128) / xr (col>=128), bf16
#pragma unroll
  for (int m = 0; m < 4; ++m) {
    const int rbase = row0 + wr * 64 + m * 16 + (lane >> 4) * 4;
#pragma unroll
    for (int n = 0; n < 4; ++n) {
      const int c = wc * 64 + n * 16 + (lane & 15);
      bf16* dst = (c < 128) ? xl : xr;
      const int cc = c & 127;
#pragma unroll
      for (int j = 0; j < 4; ++j) {
        const int r = rbase + j;
        if (r < M) dst[(size_t)r * 128 + cc] = (bf16)acc[m][n][j];
      }
    }
  }
}

// ---------------------------------------------------------------------------
// edge phase: one wave per dst node, lane owns dims {2*lane, 2*lane+1}
// online softmax over CSR edges; bf16 feature gathers, fp32 math.
// ---------------------------------------------------------------------------
__global__ __launch_bounds__(256) void gat_edge(
    const bf16* __restrict__ xl, const bf16* __restrict__ xr,
    const int* __restrict__ row_ptr, const int* __restrict__ csr_src,
    const int* __restrict__ csr_eid, const float* __restrict__ att,
    const float* __restrict__ bias, const float* __restrict__ extra,
    bf16* __restrict__ out_b,   // layer 1: attn1 (bf16) or null
    float* __restrict__ out_f,  // layer 2: out_feat (fp32) or null
    float* __restrict__ e_ws, float* __restrict__ m_ws,
    float* __restrict__ den_ws, int N) {
  const int wave = threadIdx.x >> 6;
  const int lane = threadIdx.x & 63;
  const int node = blockIdx.x * 4 + wave;
  if (node >= N) return;

  const int d0 = lane * 2;
  const float2 attv = *(const float2*)&att[d0];
  const unsigned ur = *(const unsigned*)&xr[(size_t)node * 128 + d0];
  const float rx = __uint_as_float(ur << 16);
  const float ry = __uint_as_float(ur & 0xffff0000u);

  float m = -1e30f, den = 0.f;
  float accx = 0.f, accy = 0.f;

  const int beg = row_ptr[node];
  const int end = row_ptr[node + 1];
  for (int idx = beg; idx < end; ++idx) {
    const int s = csr_src[idx];
    const unsigned u = *(const unsigned*)&xl[(size_t)s * 128 + d0];
    const float lx = __uint_as_float(u << 16);
    const float ly = __uint_as_float(u & 0xffff0000u);
    float hx = lx + rx;
    float hy = ly + ry;
    hx = hx > 0.f ? hx : 0.2f * hx;
    hy = hy > 0.f ? hy : 0.2f * hy;
    float p = fmaf(hx, attv.x, hy * attv.y);
#pragma unroll
    for (int off = 32; off; off >>= 1) p += __shfl_xor(p, off);
    if (e_ws != nullptr && lane == 0) e_ws[csr_eid[idx]] = p;
    if (p > m) {
      const float f = __expf(m - p);  // 0 on first edge
      den = den * f + 1.f;
      accx = accx * f + lx;
      accy = accy * f + ly;
      m = p;
    } else {
      const float wgt = __expf(p - m);
      den += wgt;
      accx = fmaf(wgt, lx, accx);
      accy = fmaf(wgt, ly, accy);
    }
  }

  const float inv = 1.f / den;
  float ox = accx * inv + bias[d0];
  float oy = accy * inv + bias[d0 + 1];
  if (extra != nullptr) { ox += extra[d0]; oy += extra[d0 + 1]; }
  if (out_b != nullptr) {
    const unsigned packed =
        (unsigned)bf16_bits(ox) | ((unsigned)bf16_bits(oy) << 16);
    *(unsigned*)&out_b[(size_t)node * 128 + d0] = packed;
  }
  if (out_f != nullptr) {
    *(float2*)&out_f[(size_t)node * 128 + d0] = make_float2(ox, oy);
  }
  if (m_ws != nullptr && lane == 0) {
    m_ws[node] = m;
    den_ws[node] = den;
  }
}

__global__ void alpha_kernel(const float* __restrict__ e_ws,
                             const float* __restrict__ m_ws,
                             const float* __restrict__ den_ws,
                             const int* __restrict__ ei, int E, int N,
                             float* __restrict__ out_alpha) {
  const int i = blockIdx.x * blockDim.x + threadIdx.x;
  if (i >= E + N) return;
  const int d = (i < E) ? ei[E + i] : (i - E);
  out_alpha[i] = __expf(e_ws[i] - m_ws[d]) / den_ws[d];
}

// ---------------------------------------------------------------------------
extern "C" void kernel_launch(void* const* d_in, const int* in_sizes, int n_in,
                              void* d_out, int out_size, void* d_ws,
                              size_t ws_size, hipStream_t stream) {
  const float* x          = (const float*)d_in[0];
  const int*   ei         = (const int*)d_in[1];
  const float* mmse_score = (const float*)d_in[2];
  const float* W_l1       = (const float*)d_in[3];
  const float* W_r1       = (const float*)d_in[4];
  const float* att1       = (const float*)d_in[5];
  const float* bias1      = (const float*)d_in[6];
  const float* W_l2       = (const float*)d_in[7];
  const float* W_r2       = (const float*)d_in[8];
  const float* att2       = (const float*)d_in[9];
  const float* bias2      = (const float*)d_in[10];
  const float* mmse_W     = (const float*)d_in[11];
  const float* mmse_b     = (const float*)d_in[12];

  const int D  = in_sizes[5];      // 128
  const int T  = in_sizes[3] / D;  // 512
  const int N  = in_sizes[0] / T;  // 50000
  const int E  = in_sizes[1] / 2;  // 800000
  const int ET = E + N;

  char* wptr = (char*)d_ws;
  auto alloc = [&](size_t bytes) {
    char* p = wptr;
    wptr += (bytes + 255) & ~(size_t)255;
    return p;
  };
  bf16* xl      = (bf16*)alloc((size_t)N * 128 * 2);
  bf16* xr      = (bf16*)alloc((size_t)N * 128 * 2);
  bf16* attn1   = (bf16*)alloc((size_t)N * 128 * 2);
  bf16* Wt1     = (bf16*)alloc((size_t)256 * T * 2);
  bf16* Wt2     = (bf16*)alloc((size_t)256 * D * 2);
  float* e_ws   = (float*)alloc((size_t)ET * 4);
  float* m_ws   = (float*)alloc((size_t)N * 4);
  float* den_ws = (float*)alloc((size_t)N * 4);
  float* mmse_vec = (float*)alloc(512);
  int* counts  = (int*)alloc((size_t)N * 4);
  int* row_ptr = (int*)alloc((size_t)(N + 1) * 4);
  int* cursor  = (int*)alloc((size_t)N * 4);
  int* csr_src = (int*)alloc((size_t)ET * 4);
  int* csr_eid = (int*)alloc((size_t)ET * 4);

  float* out_feat  = (float*)d_out;             // N*128
  float* out_alpha = out_feat + (size_t)N * D;  // ET

  // 1. CSR by dst
  hipMemsetAsync(counts, 0, (size_t)N * 4, stream);
  hist_kernel<<<2048, 256, 0, stream>>>(ei, E, N, counts);
  scan_kernel<<<1, 256, 0, stream>>>(counts, row_ptr, cursor, N);
  scatter_kernel<<<2048, 256, 0, stream>>>(ei, E, N, cursor, csr_src, csr_eid);

  // 2. weight prep + mmse embedding
  wt_kernel<<<(256 * T + 255) / 256, 256, 0, stream>>>(W_l1, W_r1, Wt1, T);
  wt_kernel<<<(256 * D + 255) / 256, 256, 0, stream>>>(W_l2, W_r2, Wt2, D);
  mmse_kernel<<<1, 128, 0, stream>>>(mmse_score, mmse_W, mmse_b, mmse_vec, D);

  // 3. layer-1 GEMM (fp32 A, converts inline) -> xl/xr bf16
  const int gblocks = (N + 127) / 128;
  gemm_mfma<true><<<gblocks, 512, 0, stream>>>(x, Wt1, xl, xr, N, T);

  // 4. layer-1 edge phase -> attn1 bf16, logits for alpha
  gat_edge<<<(N + 3) / 4, 256, 0, stream>>>(xl, xr, row_ptr, csr_src, csr_eid,
                                            att1, bias1, nullptr, attn1,
                                            nullptr, e_ws, m_ws, den_ws, N);

  // 5. alpha in original edge order
  alpha_kernel<<<(ET + 255) / 256, 256, 0, stream>>>(e_ws, m_ws, den_ws, ei, E,
                                                     N, out_alpha);

  // 6. layer-2 GEMM (bf16 A = attn1) -> xl/xr reused
  gemm_mfma<false><<<gblocks, 512, 0, stream>>>(attn1, Wt2, xl, xr, N, D);

  // 7. layer-2 edge phase -> out_feat fp32 (+ mmse embedding)
  gat_edge<<<(N + 3) / 4, 256, 0, stream>>>(xl, xr, row_ptr, csr_src, csr_eid,
                                            att2, bias2, mmse_vec, nullptr,
                                            out_feat, nullptr, nullptr, nullptr,
                                            N);
}

// Round 4
// 624.390 us; speedup vs baseline: 1.4291x; 1.0942x over previous
//
#include <hip/hip_runtime.h>
#include <cstdint>

typedef __bf16 bf16;
typedef __bf16 bf16x8 __attribute__((ext_vector_type(8)));
typedef float f32x4 __attribute__((ext_vector_type(4)));

__device__ __forceinline__ void load_lds16(const void* g, void* l) {
  __builtin_amdgcn_global_load_lds(
      (const __attribute__((address_space(1))) void*)g,
      (__attribute__((address_space(3))) void*)l, 16, 0, 0);
}

__device__ __forceinline__ unsigned short bf16_bits(float f) {
  return __builtin_bit_cast(unsigned short, (bf16)f);
}

// ---------------------------------------------------------------------------
// CSR-by-dst build
// ---------------------------------------------------------------------------
__global__ void hist_kernel(const int* __restrict__ ei, int E, int N,
                            int* __restrict__ counts) {
  const int total = E + N;
  for (int i = blockIdx.x * blockDim.x + threadIdx.x; i < total;
       i += gridDim.x * blockDim.x) {
    const int d = (i < E) ? ei[E + i] : (i - E);
    atomicAdd(&counts[d], 1);
  }
}

__global__ void scan_kernel(const int* __restrict__ counts,
                            int* __restrict__ row_ptr,
                            int* __restrict__ cursor, int N) {
  __shared__ int sums[257];
  const int tid = threadIdx.x;  // 256 threads
  const int chunk = (N + 255) / 256;
  const int lo = tid * chunk;
  const int hi = min(lo + chunk, N);
  int s = 0;
  for (int i = lo; i < hi; ++i) s += counts[i];
  sums[tid + 1] = s;
  if (tid == 0) sums[0] = 0;
  __syncthreads();
  if (tid == 0) {
    for (int i = 1; i <= 256; ++i) sums[i] += sums[i - 1];
  }
  __syncthreads();
  int run = sums[tid];
  for (int i = lo; i < hi; ++i) {
    row_ptr[i] = run;
    cursor[i] = run;
    run += counts[i];
  }
  if (tid == 255) row_ptr[N] = sums[256];
}

__global__ void scatter_kernel(const int* __restrict__ ei, int E, int N,
                               int* __restrict__ cursor,
                               int* __restrict__ csr_src,
                               int* __restrict__ csr_eid) {
  const int total = E + N;
  for (int i = blockIdx.x * blockDim.x + threadIdx.x; i < total;
       i += gridDim.x * blockDim.x) {
    int s, d;
    if (i < E) { s = ei[i]; d = ei[E + i]; } else { s = d = i - E; }
    const int pos = atomicAdd(&cursor[d], 1);
    csr_src[pos] = s;
    csr_eid[pos] = i;
  }
}

// ---------------------------------------------------------------------------
// small helpers
// ---------------------------------------------------------------------------
__global__ void mmse_kernel(const float* __restrict__ score,
                            const float* __restrict__ W,
                            const float* __restrict__ b,
                            float* __restrict__ out, int D) {
  const int i = threadIdx.x;
  if (i < D) out[i] = score[0] * W[i] + b[i];
}

// Wt[col][k] (col-major weights, bf16), col in [0,256): 0..127 = W_l, 128..255 = W_r
__global__ void wt_kernel(const float* __restrict__ Wl,
                          const float* __restrict__ Wr,
                          bf16* __restrict__ Wt, int K) {
  const int idx = blockIdx.x * blockDim.x + threadIdx.x;
  if (idx >= 256 * K) return;
  const int col = idx & 255;
  const int k = idx >> 8;
  const float v = (col < 128) ? Wl[k * 128 + col] : Wr[k * 128 + (col - 128)];
  Wt[(size_t)col * K + k] = (bf16)v;
}

// ---------------------------------------------------------------------------
// MFMA GEMM: [xl | xr] = A[M][K] @ Wt^T   (Wt is [256][K] bf16, col-major W)
// BM=128, BN=256, BK=32; 512 threads = 8 waves (2x4), 64x64 per wave.
// ---------------------------------------------------------------------------
template <bool AF32>
__global__ __launch_bounds__(512) void gemm_mfma(
    const void* __restrict__ Ap, const bf16* __restrict__ Wt,
    bf16* __restrict__ xl, bf16* __restrict__ xr, int M, int K) {
  __shared__ __align__(16) bf16 Alds[128 * 32];
  __shared__ __align__(16) bf16 Blds[256 * 32];

  const int tid = threadIdx.x;
  const int w = tid >> 6, lane = tid & 63;
  const int wr = w >> 2, wc = w & 3;  // 2 x 4 waves
  const int row0 = blockIdx.x * 128;

  const int s_row = tid >> 2;
  const int s_k = (tid & 3) * 8;
  const int a_row = min(row0 + s_row, M - 1);
  bf16* a_dst = Alds + tid * 8;

  const int b_col0 = w * 32 + (lane >> 2);
  const bf16* b_src0 = Wt + (size_t)b_col0 * K + (lane & 3) * 8;
  const bf16* b_src1 = Wt + (size_t)(b_col0 + 16) * K + (lane & 3) * 8;
  bf16* b_dst0 = Blds + w * 1024 + lane * 8;
  bf16* b_dst1 = b_dst0 + 512;

  const int a_f0 = (wr * 64 + (lane & 15)) * 32 + (lane >> 4) * 8;
  const int b_f0 = (wc * 64 + (lane & 15)) * 32 + (lane >> 4) * 8;

  f32x4 acc[4][4] = {};

  for (int k0 = 0; k0 < K; k0 += 32) {
    bf16x8 av;
    if (AF32) {
      const float* A = (const float*)Ap;
      const float4 f0 = *(const float4*)&A[(size_t)a_row * K + k0 + s_k];
      const float4 f1 = *(const float4*)&A[(size_t)a_row * K + k0 + s_k + 4];
      av[0] = (bf16)f0.x; av[1] = (bf16)f0.y; av[2] = (bf16)f0.z; av[3] = (bf16)f0.w;
      av[4] = (bf16)f1.x; av[5] = (bf16)f1.y; av[6] = (bf16)f1.z; av[7] = (bf16)f1.w;
    } else {
      av = *(const bf16x8*)((const bf16*)Ap + (size_t)a_row * K + k0 + s_k);
    }
    __syncthreads();
    *(bf16x8*)a_dst = av;
    load_lds16(b_src0 + k0, b_dst0);
    load_lds16(b_src1 + k0, b_dst1);
    __syncthreads();

    bf16x8 af[4], bfr[4];
#pragma unroll
    for (int m = 0; m < 4; ++m) af[m] = *(const bf16x8*)(Alds + a_f0 + m * 512);
#pragma unroll
    for (int n = 0; n < 4; ++n) bfr[n] = *(const bf16x8*)(Blds + b_f0 + n * 512);
#pragma unroll
    for (int m = 0; m < 4; ++m)
#pragma unroll
      for (int n = 0; n < 4; ++n)
        acc[m][n] = __builtin_amdgcn_mfma_f32_16x16x32_bf16(af[m], bfr[n],
                                                            acc[m][n], 0, 0, 0);
  }

#pragma unroll
  for (int m = 0; m < 4; ++m) {
    const int rbase = row0 + wr * 64 + m * 16 + (lane >> 4) * 4;
#pragma unroll
    for (int n = 0; n < 4; ++n) {
      const int c = wc * 64 + n * 16 + (lane & 15);
      bf16* dst = (c < 128) ? xl : xr;
      const int cc = c & 127;
#pragma unroll
      for (int j = 0; j < 4; ++j) {
        const int r = rbase + j;
        if (r < M) dst[(size_t)r * 128 + cc] = (bf16)acc[m][n][j];
      }
    }
  }
}

// ---------------------------------------------------------------------------
// edge phase: one wave per dst node, lane owns dims {2*lane, 2*lane+1}.
// Batched online softmax: 8 edges per iteration -> 8 outstanding gathers,
// 8 pipelined shuffle-reduce chains, one rescale per batch.
// beg/end/idx are wave-uniform, so all j-guards are uniform branches.
// ---------------------------------------------------------------------------
__global__ __launch_bounds__(256) void gat_edge(
    const bf16* __restrict__ xl, const bf16* __restrict__ xr,
    const int* __restrict__ row_ptr, const int* __restrict__ csr_src,
    const int* __restrict__ csr_eid, const float* __restrict__ att,
    const float* __restrict__ bias, const float* __restrict__ extra,
    bf16* __restrict__ out_b,   // layer 1: attn1 (bf16) or null
    float* __restrict__ out_f,  // layer 2: out_feat (fp32) or null
    float* __restrict__ e_ws, float* __restrict__ m_ws,
    float* __restrict__ den_ws, int N) {
  const int wave = threadIdx.x >> 6;
  const int lane = threadIdx.x & 63;
  const int node = blockIdx.x * 4 + wave;
  if (node >= N) return;

  const int d0 = lane * 2;
  const float2 attv = *(const float2*)&att[d0];
  const unsigned ur = *(const unsigned*)&xr[(size_t)node * 128 + d0];
  const float rx = __uint_as_float(ur << 16);
  const float ry = __uint_as_float(ur & 0xffff0000u);

  float m = -1e30f, den = 0.f;
  float accx = 0.f, accy = 0.f;

  const int beg = row_ptr[node];
  const int end = row_ptr[node + 1];

  for (int idx = beg; idx < end; idx += 8) {
    const int rem = end - idx;  // >= 1, wave-uniform

    int s[8], eid[8];
#pragma unroll
    for (int j = 0; j < 8; ++j) {
      const int k = (j < rem) ? idx + j : idx;
      s[j] = csr_src[k];
      eid[j] = csr_eid[k];
    }

    unsigned u[8];
#pragma unroll
    for (int j = 0; j < 8; ++j)
      u[j] = *(const unsigned*)&xl[(size_t)s[j] * 128 + d0];

    float lx[8], ly[8], p[8];
#pragma unroll
    for (int j = 0; j < 8; ++j) {
      lx[j] = __uint_as_float(u[j] << 16);
      ly[j] = __uint_as_float(u[j] & 0xffff0000u);
      float hx = lx[j] + rx;
      float hy = ly[j] + ry;
      hx = hx > 0.f ? hx : 0.2f * hx;
      hy = hy > 0.f ? hy : 0.2f * hy;
      p[j] = fmaf(hx, attv.x, hy * attv.y);
    }

#pragma unroll
    for (int off = 32; off; off >>= 1) {
#pragma unroll
      for (int j = 0; j < 8; ++j) p[j] += __shfl_xor(p[j], off);
    }

#pragma unroll
    for (int j = 0; j < 8; ++j)
      if (j >= rem) p[j] = -1e30f;  // masked lanes contribute weight 0

    if (e_ws != nullptr && lane == 0) {
#pragma unroll
      for (int j = 0; j < 8; ++j)
        if (j < rem) e_ws[eid[j]] = p[j];
    }

    float bm = fmaxf(fmaxf(fmaxf(p[0], p[1]), fmaxf(p[2], p[3])),
                     fmaxf(fmaxf(p[4], p[5]), fmaxf(p[6], p[7])));
    if (bm > m) {
      const float f = __expf(m - bm);  // 0 on the first batch
      den *= f;
      accx *= f;
      accy *= f;
      m = bm;
    }
#pragma unroll
    for (int j = 0; j < 8; ++j) {
      const float wgt = __expf(p[j] - m);
      den += wgt;
      accx = fmaf(wgt, lx[j], accx);
      accy = fmaf(wgt, ly[j], accy);
    }
  }

  const float inv = 1.f / den;
  float ox = accx * inv + bias[d0];
  float oy = accy * inv + bias[d0 + 1];
  if (extra != nullptr) { ox += extra[d0]; oy += extra[d0 + 1]; }
  if (out_b != nullptr) {
    const unsigned packed =
        (unsigned)bf16_bits(ox) | ((unsigned)bf16_bits(oy) << 16);
    *(unsigned*)&out_b[(size_t)node * 128 + d0] = packed;
  }
  if (out_f != nullptr) {
    *(float2*)&out_f[(size_t)node * 128 + d0] = make_float2(ox, oy);
  }
  if (m_ws != nullptr && lane == 0) {
    m_ws[node] = m;
    den_ws[node] = den;
  }
}

__global__ void alpha_kernel(const float* __restrict__ e_ws,
                             const float* __restrict__ m_ws,
                             const float* __restrict__ den_ws,
                             const int* __restrict__ ei, int E, int N,
                             float* __restrict__ out_alpha) {
  const int i = blockIdx.x * blockDim.x + threadIdx.x;
  if (i >= E + N) return;
  const int d = (i < E) ? ei[E + i] : (i - E);
  out_alpha[i] = __expf(e_ws[i] - m_ws[d]) / den_ws[d];
}

// ---------------------------------------------------------------------------
extern "C" void kernel_launch(void* const* d_in, const int* in_sizes, int n_in,
                              void* d_out, int out_size, void* d_ws,
                              size_t ws_size, hipStream_t stream) {
  const float* x          = (const float*)d_in[0];
  const int*   ei         = (const int*)d_in[1];
  const float* mmse_score = (const float*)d_in[2];
  const float* W_l1       = (const float*)d_in[3];
  const float* W_r1       = (const float*)d_in[4];
  const float* att1       = (const float*)d_in[5];
  const float* bias1      = (const float*)d_in[6];
  const float* W_l2       = (const float*)d_in[7];
  const float* W_r2       = (const float*)d_in[8];
  const float* att2       = (const float*)d_in[9];
  const float* bias2      = (const float*)d_in[10];
  const float* mmse_W     = (const float*)d_in[11];
  const float* mmse_b     = (const float*)d_in[12];

  const int D  = in_sizes[5];      // 128
  const int T  = in_sizes[3] / D;  // 512
  const int N  = in_sizes[0] / T;  // 50000
  const int E  = in_sizes[1] / 2;  // 800000
  const int ET = E + N;

  char* wptr = (char*)d_ws;
  auto alloc = [&](size_t bytes) {
    char* p = wptr;
    wptr += (bytes + 255) & ~(size_t)255;
    return p;
  };
  bf16* xl      = (bf16*)alloc((size_t)N * 128 * 2);
  bf16* xr      = (bf16*)alloc((size_t)N * 128 * 2);
  bf16* attn1   = (bf16*)alloc((size_t)N * 128 * 2);
  bf16* Wt1     = (bf16*)alloc((size_t)256 * T * 2);
  bf16* Wt2     = (bf16*)alloc((size_t)256 * D * 2);
  float* e_ws   = (float*)alloc((size_t)ET * 4);
  float* m_ws   = (float*)alloc((size_t)N * 4);
  float* den_ws = (float*)alloc((size_t)N * 4);
  float* mmse_vec = (float*)alloc(512);
  int* counts  = (int*)alloc((size_t)N * 4);
  int* row_ptr = (int*)alloc((size_t)(N + 1) * 4);
  int* cursor  = (int*)alloc((size_t)N * 4);
  int* csr_src = (int*)alloc((size_t)ET * 4);
  int* csr_eid = (int*)alloc((size_t)ET * 4);

  float* out_feat  = (float*)d_out;             // N*128
  float* out_alpha = out_feat + (size_t)N * D;  // ET

  // 1. CSR by dst
  hipMemsetAsync(counts, 0, (size_t)N * 4, stream);
  hist_kernel<<<2048, 256, 0, stream>>>(ei, E, N, counts);
  scan_kernel<<<1, 256, 0, stream>>>(counts, row_ptr, cursor, N);
  scatter_kernel<<<2048, 256, 0, stream>>>(ei, E, N, cursor, csr_src, csr_eid);

  // 2. weight prep + mmse embedding
  wt_kernel<<<(256 * T + 255) / 256, 256, 0, stream>>>(W_l1, W_r1, Wt1, T);
  wt_kernel<<<(256 * D + 255) / 256, 256, 0, stream>>>(W_l2, W_r2, Wt2, D);
  mmse_kernel<<<1, 128, 0, stream>>>(mmse_score, mmse_W, mmse_b, mmse_vec, D);

  // 3. layer-1 GEMM (fp32 A, converts inline) -> xl/xr bf16
  const int gblocks = (N + 127) / 128;
  gemm_mfma<true><<<gblocks, 512, 0, stream>>>(x, Wt1, xl, xr, N, T);

  // 4. layer-1 edge phase -> attn1 bf16, logits for alpha
  gat_edge<<<(N + 3) / 4, 256, 0, stream>>>(xl, xr, row_ptr, csr_src, csr_eid,
                                            att1, bias1, nullptr, attn1,
                                            nullptr, e_ws, m_ws, den_ws, N);

  // 5. alpha in original edge order
  alpha_kernel<<<(ET + 255) / 256, 256, 0, stream>>>(e_ws, m_ws, den_ws, ei, E,
                                                     N, out_alpha);

  // 6. layer-2 GEMM (bf16 A = attn1) -> xl/xr reused
  gemm_mfma<false><<<gblocks, 512, 0, stream>>>(attn1, Wt2, xl, xr, N, D);

  // 7. layer-2 edge phase -> out_feat fp32 (+ mmse embedding)
  gat_edge<<<(N + 3) / 4, 256, 0, stream>>>(xl, xr, row_ptr, csr_src, csr_eid,
                                            att2, bias2, mmse_vec, nullptr,
                                            out_feat, nullptr, nullptr, nullptr,
                                            N);
}

// Round 5
// 447.302 us; speedup vs baseline: 1.9949x; 1.3959x over previous
//
#include <hip/hip_runtime.h>
#include <cstdint>

typedef __bf16 bf16;
typedef __bf16 bf16x8 __attribute__((ext_vector_type(8)));
typedef float f32x4 __attribute__((ext_vector_type(4)));

__device__ __forceinline__ void load_lds16(const void* g, void* l) {
  __builtin_amdgcn_global_load_lds(
      (const __attribute__((address_space(1))) void*)g,
      (__attribute__((address_space(3))) void*)l, 16, 0, 0);
}

__device__ __forceinline__ unsigned short bf16_bits(float f) {
  return __builtin_bit_cast(unsigned short, (bf16)f);
}
__device__ __forceinline__ float bf_lo(unsigned u) {
  return __uint_as_float(u << 16);
}
__device__ __forceinline__ float bf_hi(unsigned u) {
  return __uint_as_float(u & 0xffff0000u);
}

// ---------------------------------------------------------------------------
// CSR-by-dst build
// ---------------------------------------------------------------------------
__global__ void hist_kernel(const int* __restrict__ ei, int E, int N,
                            int* __restrict__ counts) {
  const int total = E + N;
  for (int i = blockIdx.x * blockDim.x + threadIdx.x; i < total;
       i += gridDim.x * blockDim.x) {
    const int d = (i < E) ? ei[E + i] : (i - E);
    atomicAdd(&counts[d], 1);
  }
}

// 3-phase parallel exclusive scan over counts[N] (256 blocks).
__global__ void scan_reduce(const int* __restrict__ counts,
                            int* __restrict__ bsum, int N) {
  __shared__ int red[256];
  const int chunk = (N + 255) / 256;
  const int lo = blockIdx.x * chunk;
  const int hi = min(lo + chunk, N);
  int s = 0;
  for (int i = lo + threadIdx.x; i < hi; i += 256) s += counts[i];
  red[threadIdx.x] = s;
  __syncthreads();
  for (int off = 128; off; off >>= 1) {
    if (threadIdx.x < off) red[threadIdx.x] += red[threadIdx.x + off];
    __syncthreads();
  }
  if (threadIdx.x == 0) bsum[blockIdx.x] = red[0];
}

__global__ void scan_bsum(int* __restrict__ bsum, int* __restrict__ row_ptr,
                          int N) {
  __shared__ int tmp[256];
  const int tid = threadIdx.x;
  const int v = bsum[tid];
  tmp[tid] = v;
  __syncthreads();
  for (int off = 1; off < 256; off <<= 1) {
    const int t = (tid >= off) ? tmp[tid - off] : 0;
    __syncthreads();
    tmp[tid] += t;
    __syncthreads();
  }
  bsum[tid] = tmp[tid] - v;  // exclusive block offsets
  if (tid == 255) row_ptr[N] = tmp[255];
}

__global__ void scan_write(const int* __restrict__ counts,
                           const int* __restrict__ boff,
                           int* __restrict__ row_ptr, int* __restrict__ cursor,
                           int N) {
  __shared__ int tmp[256];
  const int chunk = (N + 255) / 256;
  const int lo = blockIdx.x * chunk;
  const int hi = min(lo + chunk, N);
  int carry = boff[blockIdx.x];
  for (int base = lo; base < hi; base += 256) {
    const int i = base + threadIdx.x;
    const int v = (i < hi) ? counts[i] : 0;
    tmp[threadIdx.x] = v;
    __syncthreads();
    for (int off = 1; off < 256; off <<= 1) {
      const int t = (threadIdx.x >= off) ? tmp[threadIdx.x - off] : 0;
      __syncthreads();
      tmp[threadIdx.x] += t;
      __syncthreads();
    }
    if (i < hi) {
      const int excl = carry + tmp[threadIdx.x] - v;
      row_ptr[i] = excl;
      cursor[i] = excl;
    }
    carry += tmp[255];
    __syncthreads();
  }
}

__global__ void scatter_kernel(const int* __restrict__ ei, int E, int N,
                               int* __restrict__ cursor,
                               int* __restrict__ csr_src,
                               int* __restrict__ csr_eid) {
  const int total = E + N;
  for (int i = blockIdx.x * blockDim.x + threadIdx.x; i < total;
       i += gridDim.x * blockDim.x) {
    int s, d;
    if (i < E) { s = ei[i]; d = ei[E + i]; } else { s = d = i - E; }
    const int pos = atomicAdd(&cursor[d], 1);
    csr_src[pos] = s;
    csr_eid[pos] = i;
  }
}

// ---------------------------------------------------------------------------
// small helpers
// ---------------------------------------------------------------------------
__global__ void mmse_kernel(const float* __restrict__ score,
                            const float* __restrict__ W,
                            const float* __restrict__ b,
                            float* __restrict__ out, int D) {
  const int i = threadIdx.x;
  if (i < D) out[i] = score[0] * W[i] + b[i];
}

__global__ void wt_kernel(const float* __restrict__ Wl,
                          const float* __restrict__ Wr,
                          bf16* __restrict__ Wt, int K) {
  const int idx = blockIdx.x * blockDim.x + threadIdx.x;
  if (idx >= 256 * K) return;
  const int col = idx & 255;
  const int k = idx >> 8;
  const float v = (col < 128) ? Wl[k * 128 + col] : Wr[k * 128 + (col - 128)];
  Wt[(size_t)col * K + k] = (bf16)v;
}

// ---------------------------------------------------------------------------
// MFMA GEMM: [xl | xr] = A[M][K] @ Wt^T   (Wt is [256][K] bf16, col-major W)
// BM=128, BN=256, BK=32; 512 threads = 8 waves (2x4), 64x64 per wave.
// ---------------------------------------------------------------------------
template <bool AF32>
__global__ __launch_bounds__(512) void gemm_mfma(
    const void* __restrict__ Ap, const bf16* __restrict__ Wt,
    bf16* __restrict__ xl, bf16* __restrict__ xr, int M, int K) {
  __shared__ __align__(16) bf16 Alds[128 * 32];
  __shared__ __align__(16) bf16 Blds[256 * 32];

  const int tid = threadIdx.x;
  const int w = tid >> 6, lane = tid & 63;
  const int wr = w >> 2, wc = w & 3;
  const int row0 = blockIdx.x * 128;

  const int s_row = tid >> 2;
  const int s_k = (tid & 3) * 8;
  const int a_row = min(row0 + s_row, M - 1);
  bf16* a_dst = Alds + tid * 8;

  const int b_col0 = w * 32 + (lane >> 2);
  const bf16* b_src0 = Wt + (size_t)b_col0 * K + (lane & 3) * 8;
  const bf16* b_src1 = Wt + (size_t)(b_col0 + 16) * K + (lane & 3) * 8;
  bf16* b_dst0 = Blds + w * 1024 + lane * 8;
  bf16* b_dst1 = b_dst0 + 512;

  const int a_f0 = (wr * 64 + (lane & 15)) * 32 + (lane >> 4) * 8;
  const int b_f0 = (wc * 64 + (lane & 15)) * 32 + (lane >> 4) * 8;

  f32x4 acc[4][4] = {};

  for (int k0 = 0; k0 < K; k0 += 32) {
    bf16x8 av;
    if (AF32) {
      const float* A = (const float*)Ap;
      const float4 f0 = *(const float4*)&A[(size_t)a_row * K + k0 + s_k];
      const float4 f1 = *(const float4*)&A[(size_t)a_row * K + k0 + s_k + 4];
      av[0] = (bf16)f0.x; av[1] = (bf16)f0.y; av[2] = (bf16)f0.z; av[3] = (bf16)f0.w;
      av[4] = (bf16)f1.x; av[5] = (bf16)f1.y; av[6] = (bf16)f1.z; av[7] = (bf16)f1.w;
    } else {
      av = *(const bf16x8*)((const bf16*)Ap + (size_t)a_row * K + k0 + s_k);
    }
    __syncthreads();
    *(bf16x8*)a_dst = av;
    load_lds16(b_src0 + k0, b_dst0);
    load_lds16(b_src1 + k0, b_dst1);
    __syncthreads();

    bf16x8 af[4], bfr[4];
#pragma unroll
    for (int m = 0; m < 4; ++m) af[m] = *(const bf16x8*)(Alds + a_f0 + m * 512);
#pragma unroll
    for (int n = 0; n < 4; ++n) bfr[n] = *(const bf16x8*)(Blds + b_f0 + n * 512);
#pragma unroll
    for (int m = 0; m < 4; ++m)
#pragma unroll
      for (int n = 0; n < 4; ++n)
        acc[m][n] = __builtin_amdgcn_mfma_f32_16x16x32_bf16(af[m], bfr[n],
                                                            acc[m][n], 0, 0, 0);
  }

#pragma unroll
  for (int m = 0; m < 4; ++m) {
    const int rbase = row0 + wr * 64 + m * 16 + (lane >> 4) * 4;
#pragma unroll
    for (int n = 0; n < 4; ++n) {
      const int c = wc * 64 + n * 16 + (lane & 15);
      bf16* dst = (c < 128) ? xl : xr;
      const int cc = c & 127;
#pragma unroll
      for (int j = 0; j < 4; ++j) {
        const int r = rbase + j;
        if (r < M) dst[(size_t)r * 128 + cc] = (bf16)acc[m][n][j];
      }
    }
  }
}

// ---------------------------------------------------------------------------
// edge phase v3: 2 nodes per wave (32-lane halves), 4 dims per lane,
// 8-edge batches. Latency chain per wave ~= max(degA,degB)/8 generations.
// ---------------------------------------------------------------------------
__global__ __launch_bounds__(256) void gat_edge(
    const bf16* __restrict__ xl, const bf16* __restrict__ xr,
    const int* __restrict__ row_ptr, const int* __restrict__ csr_src,
    const int* __restrict__ csr_eid, const float* __restrict__ att,
    const float* __restrict__ bias, const float* __restrict__ extra,
    bf16* __restrict__ out_b,   // layer 1: attn1 (bf16) or null
    float* __restrict__ out_f,  // layer 2: out_feat (fp32) or null
    float* __restrict__ e_ws, float* __restrict__ m_ws,
    float* __restrict__ den_ws, int N) {
  const int wave = threadIdx.x >> 6;
  const int lane = threadIdx.x & 63;
  const int l5 = lane & 31;
  const int half = lane >> 5;
  const int node_raw = blockIdx.x * 8 + wave * 2 + half;
  const bool vnode = node_raw < N;
  const int node = vnode ? node_raw : N - 1;

  const int d0 = l5 * 4;
  const float4 attv = *(const float4*)&att[d0];
  const uint2 ur = *(const uint2*)&xr[(size_t)node * 128 + d0];
  const float r0 = bf_lo(ur.x), r1 = bf_hi(ur.x);
  const float r2 = bf_lo(ur.y), r3 = bf_hi(ur.y);

  float m = -1e30f, den = 0.f;
  float a0 = 0.f, a1 = 0.f, a2 = 0.f, a3 = 0.f;

  const int beg = vnode ? row_ptr[node] : 0;
  const int end = vnode ? row_ptr[node + 1] : 0;
  const int nbat = (end - beg + 7) >> 3;
  const int nloop = max(nbat, __shfl_xor(nbat, 32));

  for (int t = 0; t < nloop; ++t) {
    const int idx = beg + t * 8;

    int s[8];
#pragma unroll
    for (int j = 0; j < 8; ++j) {
      const int k = idx + j;
      s[j] = csr_src[(k < end) ? k : beg];
    }
    int eid[8];
    if (e_ws != nullptr) {
#pragma unroll
      for (int j = 0; j < 8; ++j) {
        const int k = idx + j;
        eid[j] = csr_eid[(k < end) ? k : beg];
      }
    }

    uint2 u[8];
#pragma unroll
    for (int j = 0; j < 8; ++j)
      u[j] = *(const uint2*)&xl[(size_t)s[j] * 128 + d0];

    float p[8];
#pragma unroll
    for (int j = 0; j < 8; ++j) {
      float h0 = bf_lo(u[j].x) + r0;
      float h1 = bf_hi(u[j].x) + r1;
      float h2 = bf_lo(u[j].y) + r2;
      float h3 = bf_hi(u[j].y) + r3;
      h0 = h0 > 0.f ? h0 : 0.2f * h0;
      h1 = h1 > 0.f ? h1 : 0.2f * h1;
      h2 = h2 > 0.f ? h2 : 0.2f * h2;
      h3 = h3 > 0.f ? h3 : 0.2f * h3;
      p[j] = fmaf(h0, attv.x, fmaf(h1, attv.y, fmaf(h2, attv.z, h3 * attv.w)));
    }

    // reduce within each 32-lane half (offsets preserve the half bit)
#pragma unroll
    for (int off = 16; off; off >>= 1) {
#pragma unroll
      for (int j = 0; j < 8; ++j) p[j] += __shfl_xor(p[j], off);
    }

#pragma unroll
    for (int j = 0; j < 8; ++j)
      if (idx + j >= end) p[j] = -1e30f;

    if (e_ws != nullptr && l5 == 0) {
#pragma unroll
      for (int j = 0; j < 8; ++j)
        if (idx + j < end) e_ws[eid[j]] = p[j];
    }

    const float bm = fmaxf(fmaxf(fmaxf(p[0], p[1]), fmaxf(p[2], p[3])),
                           fmaxf(fmaxf(p[4], p[5]), fmaxf(p[6], p[7])));
    if (bm > m) {
      const float f = __expf(m - bm);
      den *= f;
      a0 *= f; a1 *= f; a2 *= f; a3 *= f;
      m = bm;
    }
#pragma unroll
    for (int j = 0; j < 8; ++j) {
      const float wgt = __expf(p[j] - m);
      den += wgt;
      a0 = fmaf(wgt, bf_lo(u[j].x), a0);
      a1 = fmaf(wgt, bf_hi(u[j].x), a1);
      a2 = fmaf(wgt, bf_lo(u[j].y), a2);
      a3 = fmaf(wgt, bf_hi(u[j].y), a3);
    }
  }

  if (!vnode) return;

  const float inv = 1.f / den;
  const float4 bv = *(const float4*)&bias[d0];
  float o0 = fmaf(a0, inv, bv.x);
  float o1 = fmaf(a1, inv, bv.y);
  float o2 = fmaf(a2, inv, bv.z);
  float o3 = fmaf(a3, inv, bv.w);
  if (extra != nullptr) {
    const float4 ev = *(const float4*)&extra[d0];
    o0 += ev.x; o1 += ev.y; o2 += ev.z; o3 += ev.w;
  }
  if (out_b != nullptr) {
    uint2 pk;
    pk.x = (unsigned)bf16_bits(o0) | ((unsigned)bf16_bits(o1) << 16);
    pk.y = (unsigned)bf16_bits(o2) | ((unsigned)bf16_bits(o3) << 16);
    *(uint2*)&out_b[(size_t)node * 128 + d0] = pk;
  }
  if (out_f != nullptr) {
    float4 ov; ov.x = o0; ov.y = o1; ov.z = o2; ov.w = o3;
    *(float4*)&out_f[(size_t)node * 128 + d0] = ov;
  }
  if (m_ws != nullptr && l5 == 0) {
    m_ws[node] = m;
    den_ws[node] = den;
  }
}

__global__ void alpha_kernel(const float* __restrict__ e_ws,
                             const float* __restrict__ m_ws,
                             const float* __restrict__ den_ws,
                             const int* __restrict__ ei, int E, int N,
                             float* __restrict__ out_alpha) {
  const int i = blockIdx.x * blockDim.x + threadIdx.x;
  if (i >= E + N) return;
  const int d = (i < E) ? ei[E + i] : (i - E);
  out_alpha[i] = __expf(e_ws[i] - m_ws[d]) / den_ws[d];
}

// ---------------------------------------------------------------------------
extern "C" void kernel_launch(void* const* d_in, const int* in_sizes, int n_in,
                              void* d_out, int out_size, void* d_ws,
                              size_t ws_size, hipStream_t stream) {
  const float* x          = (const float*)d_in[0];
  const int*   ei         = (const int*)d_in[1];
  const float* mmse_score = (const float*)d_in[2];
  const float* W_l1       = (const float*)d_in[3];
  const float* W_r1       = (const float*)d_in[4];
  const float* att1       = (const float*)d_in[5];
  const float* bias1      = (const float*)d_in[6];
  const float* W_l2       = (const float*)d_in[7];
  const float* W_r2       = (const float*)d_in[8];
  const float* att2       = (const float*)d_in[9];
  const float* bias2      = (const float*)d_in[10];
  const float* mmse_W     = (const float*)d_in[11];
  const float* mmse_b     = (const float*)d_in[12];

  const int D  = in_sizes[5];      // 128
  const int T  = in_sizes[3] / D;  // 512
  const int N  = in_sizes[0] / T;  // 50000
  const int E  = in_sizes[1] / 2;  // 800000
  const int ET = E + N;

  char* wptr = (char*)d_ws;
  auto alloc = [&](size_t bytes) {
    char* p = wptr;
    wptr += (bytes + 255) & ~(size_t)255;
    return p;
  };
  bf16* xl      = (bf16*)alloc((size_t)N * 128 * 2);
  bf16* xr      = (bf16*)alloc((size_t)N * 128 * 2);
  bf16* attn1   = (bf16*)alloc((size_t)N * 128 * 2);
  bf16* Wt1     = (bf16*)alloc((size_t)256 * T * 2);
  bf16* Wt2     = (bf16*)alloc((size_t)256 * D * 2);
  float* e_ws   = (float*)alloc((size_t)ET * 4);
  float* m_ws   = (float*)alloc((size_t)N * 4);
  float* den_ws = (float*)alloc((size_t)N * 4);
  float* mmse_vec = (float*)alloc(512);
  int* counts  = (int*)alloc((size_t)N * 4);
  int* row_ptr = (int*)alloc((size_t)(N + 1) * 4);
  int* cursor  = (int*)alloc((size_t)N * 4);
  int* bsum    = (int*)alloc(256 * 4);
  int* csr_src = (int*)alloc((size_t)ET * 4);
  int* csr_eid = (int*)alloc((size_t)ET * 4);

  float* out_feat  = (float*)d_out;             // N*128
  float* out_alpha = out_feat + (size_t)N * D;  // ET

  // 1. CSR by dst (parallel scan)
  hipMemsetAsync(counts, 0, (size_t)N * 4, stream);
  hist_kernel<<<2048, 256, 0, stream>>>(ei, E, N, counts);
  scan_reduce<<<256, 256, 0, stream>>>(counts, bsum, N);
  scan_bsum<<<1, 256, 0, stream>>>(bsum, row_ptr, N);
  scan_write<<<256, 256, 0, stream>>>(counts, bsum, row_ptr, cursor, N);
  scatter_kernel<<<2048, 256, 0, stream>>>(ei, E, N, cursor, csr_src, csr_eid);

  // 2. weight prep + mmse embedding
  wt_kernel<<<(256 * T + 255) / 256, 256, 0, stream>>>(W_l1, W_r1, Wt1, T);
  wt_kernel<<<(256 * D + 255) / 256, 256, 0, stream>>>(W_l2, W_r2, Wt2, D);
  mmse_kernel<<<1, 128, 0, stream>>>(mmse_score, mmse_W, mmse_b, mmse_vec, D);

  // 3. layer-1 GEMM (fp32 A, converts inline) -> xl/xr bf16
  const int gblocks = (N + 127) / 128;
  gemm_mfma<true><<<gblocks, 512, 0, stream>>>(x, Wt1, xl, xr, N, T);

  // 4. layer-1 edge phase -> attn1 bf16, logits for alpha
  gat_edge<<<(N + 7) / 8, 256, 0, stream>>>(xl, xr, row_ptr, csr_src, csr_eid,
                                            att1, bias1, nullptr, attn1,
                                            nullptr, e_ws, m_ws, den_ws, N);

  // 5. alpha in original edge order
  alpha_kernel<<<(ET + 255) / 256, 256, 0, stream>>>(e_ws, m_ws, den_ws, ei, E,
                                                     N, out_alpha);

  // 6. layer-2 GEMM (bf16 A = attn1) -> xl/xr reused
  gemm_mfma<false><<<gblocks, 512, 0, stream>>>(attn1, Wt2, xl, xr, N, D);

  // 7. layer-2 edge phase -> out_feat fp32 (+ mmse embedding)
  gat_edge<<<(N + 7) / 8, 256, 0, stream>>>(xl, xr, row_ptr, csr_src, csr_eid,
                                            att2, bias2, mmse_vec, nullptr,
                                            out_feat, nullptr, nullptr, nullptr,
                                            N);
}